// Round 11
// baseline (293.387 us; speedup 1.0000x reference)
//
#include <hip/hip_runtime.h>

#define NN 163842
#define NE 983040
#define NBIN 641      // bin = dst>>8 -> 256 nodes/bin (bin 640 holds 2 nodes)
#define BINCAP 2048   // per-bin edges: mean 1536, sigma ~39 -> +13 sigma, never overflows

using short8   = __attribute__((ext_vector_type(8))) short;
using ushort8v = __attribute__((ext_vector_type(8))) unsigned short;
using f32x4    = __attribute__((ext_vector_type(4))) float;
using v2f      = __attribute__((ext_vector_type(2))) float;

static __device__ __forceinline__ unsigned short bf16rne(float x) {
    unsigned u = __float_as_uint(x);
    u += 0x7FFFu + ((u >> 16) & 1u);      // round-to-nearest-even
    return (unsigned short)(u >> 16);
}

// two bf16 (packed in a uint) -> v2f {lo, hi}
static __device__ __forceinline__ v2f bfpair(unsigned u) {
    v2f r;
    r[0] = __uint_as_float(u << 16);
    r[1] = __uint_as_float(u & 0xffff0000u);
    return r;
}

// ---- pass 1: coarse binning. Random writes become run-clustered 16-B record
// writes into per-bin regions (LDS histogram + one global atomic per block-bin).
// Round-11: 256 blocks (1/CU, was 128 = half the GPU idle) x 3840 edges = 983040 exactly.
__global__ __launch_bounds__(256) void bin_pass(const int* __restrict__ dst,
                                                const int* __restrict__ src,
                                                const float* __restrict__ ea,
                                                int* __restrict__ bincnt,
                                                int4* __restrict__ binbuf) {
    __shared__ int hist[NBIN], base[NBIN], pos[NBIN];
    const int t = threadIdx.x;
    for (int i = t; i < NBIN; i += 256) { hist[i] = 0; pos[i] = 0; }
    __syncthreads();
    const int e0 = blockIdx.x * 3840;
#pragma unroll 3
    for (int it = 0; it < 15; ++it) {
        int b = dst[e0 + it * 256 + t] >> 8;
        atomicAdd(&hist[b], 1);
    }
    __syncthreads();
    for (int i = t; i < NBIN; i += 256)
        if (hist[i] > 0) base[i] = atomicAdd(&bincnt[i], hist[i]);
    __syncthreads();
    for (int it = 0; it < 15; ++it) {
        int e = e0 + it * 256 + t;
        int d = dst[e];
        int b = d >> 8;
        int j = atomicAdd(&pos[b], 1);
        int slot = base[b] + j;
        float2 exy = *(const float2*)(ea + 2 * (size_t)e);
        int4 r;
        r.x = d; r.y = src[e];
        r.z = __float_as_int(exy.x); r.w = __float_as_int(exy.y);
        if (slot < BINCAP) binbuf[(size_t)b * BINCAP + slot] = r;
    }
}

// ---- transposed bf16 weights Wcb[n][k], k-major ----
template <int CIN, int CINP, int COUTR>
static __device__ __forceinline__ void wcb_emit(int t, const float* __restrict__ g,
                                                const float* __restrict__ root,
                                                unsigned short* __restrict__ Wcb) {
    constexpr int KTl = 4 * CINP;
    int nIdx = t / KTl, k = t - nIdx * KTl;
    int seg = k / CINP, c = k - seg * CINP;
    float v = 0.0f;
    if (c < CIN)
        v = (seg < 3) ? g[c * (3 * COUTR) + seg * COUTR + nIdx] : root[c * COUTR + nIdx];
    Wcb[t] = bf16rne(v);
}

// 3 gaussian weights from edge pseudo-coords; muv/ccv constant-indexed -> registers.
static __device__ __forceinline__ float3 gauss3c(float ex, float ey,
                                                 const float* muv, const float* ccv) {
    float3 r;
    float dx, dy;
    dx = ex - muv[0]; dy = ey - muv[1];
    r.x = __expf(fmaf(ccv[0] * dx, dx, ccv[1] * dy * dy));
    dx = ex - muv[2]; dy = ey - muv[3];
    r.y = __expf(fmaf(ccv[2] * dx, dx, ccv[3] * dy * dy));
    dx = ex - muv[4]; dy = ey - muv[5];
    r.z = __expf(fmaf(ccv[4] * dx, dx, ccv[5] * dy * dy));
    return r;
}

// ---- pass 2: one workgroup per bin. Inline exclusive bin-prefix (scan_bins launch
// removed); LDS 256-histogram + scan -> exact per-node CSR (cnt/cursor streaming,
// zero global atomics); gaussians once per edge; ged writes land in the bin's
// contiguous CSR window. pad-x and Wcb blocks appended.
__global__ __launch_bounds__(256) void build_pass(const int4* __restrict__ binbuf,
                                                  const int* __restrict__ bincnt,
                                                  int* __restrict__ cnt,
                                                  int* __restrict__ cursor,
                                                  const float* __restrict__ mu0, const float* __restrict__ sg0,
                                                  const float* __restrict__ mu1, const float* __restrict__ sg1,
                                                  const float* __restrict__ mu2, const float* __restrict__ sg2,
                                                  float4* __restrict__ ged0,
                                                  float4* __restrict__ ged1,
                                                  float4* __restrict__ ged2,
                                                  const float* __restrict__ x,
                                                  unsigned short* __restrict__ xp,
                                                  const float* __restrict__ g0, const float* __restrict__ rt0,
                                                  const float* __restrict__ g1, const float* __restrict__ rt1,
                                                  const float* __restrict__ g2, const float* __restrict__ rt2,
                                                  unsigned short* __restrict__ W0,
                                                  unsigned short* __restrict__ W1,
                                                  unsigned short* __restrict__ W2,
                                                  int PBLK, int n) {
    __shared__ int h2[256], pre[256], pos2[256];
    const int t = threadIdx.x;
    int bid = blockIdx.x;
    if (bid < NBIN) {
        // ---- inline exclusive prefix: boff = sum_{i<bid} min(bincnt[i], BINCAP) ----
        int partial = 0;
        for (int i = t; i < bid; i += 256) partial += min(bincnt[i], BINCAP);
        pre[t] = partial;
        __syncthreads();
        for (int o = 128; o > 0; o >>= 1) {
            if (t < o) pre[t] += pre[t + o];
            __syncthreads();
        }
        const int boff = pre[0];

        float muv0[6], ccv0[6], muv1[6], ccv1[6], muv2[6], ccv2[6];
#pragma unroll
        for (int j = 0; j < 6; ++j) {
            muv0[j] = mu0[j]; muv1[j] = mu1[j]; muv2[j] = mu2[j];
            float s0 = sg0[j], s1 = sg1[j], s2 = sg2[j];
            ccv0[j] = -0.5f / (1e-15f + s0 * s0);
            ccv1[j] = -0.5f / (1e-15f + s1 * s1);
            ccv2[j] = -0.5f / (1e-15f + s2 * s2);
        }
        const int total = min(bincnt[bid], BINCAP);
        const int4* bb  = binbuf + (size_t)bid * BINCAP;
        h2[t] = 0; pos2[t] = 0;
        __syncthreads();                           // also fences boff read before pre reuse
        for (int i = t; i < total; i += 256) atomicAdd(&h2[bb[i].x & 255], 1);
        __syncthreads();
        pre[t] = h2[t];
        __syncthreads();
        for (int o = 1; o < 256; o <<= 1) {
            int v = (t >= o) ? pre[t - o] : 0;
            __syncthreads();
            pre[t] += v;
            __syncthreads();
        }
        pre[t] -= h2[t];                           // exclusive
        int node = (bid << 8) + t;
        if (node < n) { cnt[node] = h2[t]; cursor[node] = boff + pre[t]; }
        __syncthreads();                           // pre[] final before random reads
        for (int i = t; i < total; i += 256) {
            int4 r = bb[i];
            int l = r.x & 255;
            int j = atomicAdd(&pos2[l], 1);
            int p = boff + pre[l] + j;
            float exf = __int_as_float(r.z), eyf = __int_as_float(r.w);
            float sb  = __int_as_float(r.y);       // src bits
            float3 G0 = gauss3c(exf, eyf, muv0, ccv0);
            float3 G1 = gauss3c(exf, eyf, muv1, ccv1);
            float3 G2 = gauss3c(exf, eyf, muv2, ccv2);
            ged0[p] = make_float4(sb, G0.x, G0.y, G0.z);
            ged1[p] = make_float4(sb, G1.x, G1.y, G1.z);
            ged2[p] = make_float4(sb, G2.x, G2.y, G2.z);
        }
        return;
    }
    bid -= NBIN;
    if (bid < PBLK) {
        // ---- pad path: one thread per node, float2 loads + ushort8 stores ----
        int r = bid * 256 + threadIdx.x;
        if (r >= n) return;
        float v[22];
        const float2* x2 = (const float2*)(x + (size_t)r * 22);  // 88 B row, 8-aligned
#pragma unroll
        for (int j = 0; j < 11; ++j) *(float2*)(v + 2 * j) = x2[j];
        unsigned short* op = xp + (size_t)r * 32;
#pragma unroll
        for (int g8 = 0; g8 < 4; ++g8) {
            ushort8v o;
#pragma unroll
            for (int j = 0; j < 8; ++j) {
                int c = g8 * 8 + j;
                o[j] = (c < 22) ? bf16rne(v[c]) : (unsigned short)0;
            }
            *(ushort8v*)(op + g8 * 8) = o;
        }
        return;
    }
    bid -= PBLK;
    int tt = bid * 256 + threadIdx.x;
    constexpr int T0 = 32 * 128, T1 = 64 * 128, T2 = 64 * 256;
    if (tt < T0)                wcb_emit<22, 32, 32>(tt, g0, rt0, W0);
    else if (tt < T0 + T1)      wcb_emit<32, 32, 64>(tt - T0, g1, rt1, W1);
    else if (tt < T0 + T1 + T2) wcb_emit<64, 64, 64>(tt - T0 - T1, g2, rt2, W2);
}

// ============ FUSED layer: aggregate (16-B bf16 gather) -> bf16 LDS tile -> MFMA ============
// Round-11: exec-masked tail gathers (was clamp-to-end-1): masked lanes issue NO memory
// request and hu is zeroed (no NaN risk from garbage x 0). Batch-4, plain launch bounds
// (round 9/10: min-waves pin causes scratch spill; plain bounds -> VGPR 40, no spill).
// Suspected regime (r7/r10 invariance): random-L3-line path ~2.6 TB/s — 2 lines/edge
// (128-B h row) is the pull-mode algorithmic floor. If dur stays ~48 again, that
// roofline is confirmed.
// Tile 64 x KT bf16, odd float4 stride conflict-free. MFMA C/D col=lane&15, row=quad*4+reg.
// FC=true: fused FC 64->2 + log_softmax through LDS (no hC traffic, no extra launch).
template <int CINP, int COUTR, int NT, bool FC>
__global__ __launch_bounds__(NT) void fused_mfma(const unsigned short* __restrict__ h, int hs,
                                                 const float4* __restrict__ ged,
                                                 const int* __restrict__ cursor,
                                                 const int* __restrict__ degi,
                                                 const unsigned short* __restrict__ Wcb,
                                                 const float* __restrict__ bias,
                                                 unsigned short* __restrict__ out,
                                                 const float* __restrict__ fcw,
                                                 const float* __restrict__ fcb,
                                                 float* __restrict__ fout, int n) {
    constexpr int KT    = 4 * CINP;
    constexpr int ST4   = KT / 8 + 1;            // float4 per LDS row (odd)
    constexpr int ROWU  = ST4 * 8;               // ushorts per LDS row
    constexpr int NSTEP = KT / 32;
    constexpr int NCT   = COUTR / 16;
    constexpr int LPN   = CINP / 8;              // lanes per node
    constexpr int NPP   = NT / LPN;              // nodes per pass
    static_assert(NPP == 64, "single pass over the 64-node tile");
    __shared__ float4 sa[64 * ST4];
    unsigned short* st = (unsigned short*)sa;
    const int row0 = blockIdx.x * 64;

    // ---------------- phase 1: aggregate + own-h into bf16 LDS tile ----------------
    {
        const int sub = threadIdx.x / LPN;
        const int li  = threadIdx.x % LPN;       // covers bf16 [li*8, li*8+8)
        int node = row0 + sub; if (node > n - 1) node = n - 1;
        int p   = cursor[node];                  // start
        int dg  = degi[node];                    // exact degree
        int end = p + dg;
        v2f a[3][4];
#pragma unroll
        for (int k = 0; k < 3; ++k)
#pragma unroll
            for (int q = 0; q < 4; ++q) a[k][q] = (v2f){0.0f, 0.0f};
        for (; p < end; p += 4) {                // batch-4, exec-masked tail
            float4 ed[4];
            uint4  hu[4];
#pragma unroll
            for (int u = 0; u < 4; ++u) {
                if (p + u < end) ed[u] = ged[p + u];
                else             ed[u] = make_float4(0.0f, 0.0f, 0.0f, 0.0f);
            }
#pragma unroll
            for (int u = 0; u < 4; ++u) {
                if (p + u < end)
                    hu[u] = *(const uint4*)(h + (long)__float_as_int(ed[u].x) * hs + li * 8);
                else
                    hu[u] = (uint4){0u, 0u, 0u, 0u};
            }
#pragma unroll
            for (int u = 0; u < 4; ++u) {
                v2f hv[4] = {bfpair(hu[u].x), bfpair(hu[u].y), bfpair(hu[u].z), bfpair(hu[u].w)};
#pragma unroll
                for (int q = 0; q < 4; ++q) {
                    a[0][q] += hv[q] * ed[u].y;
                    a[1][q] += hv[q] * ed[u].z;
                    a[2][q] += hv[q] * ed[u].w;
                }
            }
        }
        float inv = 1.0f / (float)max(dg, 1);
#pragma unroll
        for (int k = 0; k < 3; ++k)
#pragma unroll
            for (int q = 0; q < 4; ++q) a[k][q] *= inv;
        uint4 hv4 = *(const uint4*)(h + (long)node * hs + li * 8);   // raw bf16 own row
        int base = sub * ROWU;
        int c8b  = li * 8;
#pragma unroll
        for (int k = 0; k < 3; ++k) {
            ushort8v v;
#pragma unroll
            for (int q = 0; q < 4; ++q) {
                v[2 * q]     = bf16rne(a[k][q][0]);
                v[2 * q + 1] = bf16rne(a[k][q][1]);
            }
            *(ushort8v*)(st + base + k * CINP + c8b) = v;
        }
        *(uint4*)(st + base + 3 * CINP + c8b) = hv4;
    }
    __syncthreads();

    // ---------------- phase 2: MFMA GEMM from LDS tile ----------------
    constexpr int NW    = NT / 64;               // waves per block
    constexpr int TILES = 4 * NCT;               // 4 row-groups x NCT col-tiles
    constexpr int TPW   = TILES / NW;
    constexpr int RST   = NW / NCT;              // row-group stride per wave
    static_assert(NW % NCT == 0 && TILES % NW == 0, "tile remap");
    const int lane = threadIdx.x & 63;
    const int wv   = threadIdx.x >> 6;
    const int quad = lane >> 4;
    const int c16  = lane & 15;
    const int ct   = wv % NCT;                   // fixed column-tile per wave
    const int rg0  = wv / NCT;
    f32x4 acc[TPW];
#pragma unroll
    for (int i = 0; i < TPW; ++i) acc[i] = (f32x4){0.0f, 0.0f, 0.0f, 0.0f};
    const unsigned short* bcol = Wcb + (ct * 16 + c16) * KT;
#pragma unroll
    for (int s = 0; s < NSTEP; ++s) {
        short8 bf = *(const short8*)(bcol + s * 32 + quad * 8);  // hoisted: same ct all tiles
#pragma unroll
        for (int i = 0; i < TPW; ++i) {
            const unsigned short* arow = st + (16 * (rg0 + i * RST) + c16) * ROWU;
            short8 af = *(const short8*)(arow + s * 32 + quad * 8);
            acc[i] = __builtin_amdgcn_mfma_f32_16x16x32_bf16(af, bf, acc[i], 0, 0, 0);
        }
    }
    if constexpr (!FC) {
        // epilogue: C/D col=lane&15, row=quad*4+reg; write bf16
#pragma unroll
        for (int i = 0; i < TPW; ++i) {
            int rg  = rg0 + i * RST;
            int col = ct * 16 + c16;
            float b = bias[col];
#pragma unroll
            for (int r = 0; r < 4; ++r) {
                int grow = row0 + rg * 16 + quad * 4 + r;
                if (grow < n)
                    out[(long)grow * COUTR + col] = bf16rne(fmaxf(acc[i][r] + b, 0.0f));
            }
        }
    } else {
        // fused FC(64->2)+log_softmax: relu'd bf16 row -> LDS (reuse sa) -> per-node dot
        static_assert(COUTR == 64, "FC fusion assumes 64-wide rows");
        constexpr int FS = 72;                   // ushort stride, 144 B rows (16-B aligned)
        __syncthreads();                         // all MFMA LDS reads complete
        {
            int col = ct * 16 + c16;
            float b = bias[col];
#pragma unroll
            for (int i = 0; i < TPW; ++i) {
                int rg = rg0 + i * RST;
#pragma unroll
                for (int r = 0; r < 4; ++r) {
                    int lr2 = rg * 16 + quad * 4 + r;
                    st[lr2 * FS + col] = bf16rne(fmaxf(acc[i][r] + b, 0.0f));
                }
            }
        }
        __syncthreads();
        int t = threadIdx.x;
        if (t < 64) {
            int node = row0 + t;
            if (node < n) {
                const ushort8v* hr = (const ushort8v*)(st + t * FS);
                float l0 = fcb[0];
                float l1 = fcb[1];
#pragma unroll
                for (int j8 = 0; j8 < 8; ++j8) {
                    ushort8v hv = hr[j8];
#pragma unroll
                    for (int j = 0; j < 8; ++j) {
                        float hvf = __uint_as_float(((unsigned)hv[j]) << 16);
                        l0 = fmaf(hvf, fcw[2 * (8 * j8 + j)], l0);
                        l1 = fmaf(hvf, fcw[2 * (8 * j8 + j) + 1], l1);
                    }
                }
                float mx  = fmaxf(l0, l1);
                float lse = mx + logf(__expf(l0 - mx) + __expf(l1 - mx));
                fout[2 * (long)node]     = l0 - lse;
                fout[2 * (long)node + 1] = l1 - lse;
            }
        }
    }
}

extern "C" void kernel_launch(void* const* d_in, const int* in_sizes, int n_in,
                              void* d_out, int out_size, void* d_ws, size_t ws_size,
                              hipStream_t stream) {
    const float* x   = (const float*)d_in[0];
    const int*   ei  = (const int*)d_in[1];
    const float* ea  = (const float*)d_in[2];
    const float* g_[3]  = {(const float*)d_in[3],  (const float*)d_in[8],  (const float*)d_in[13]};
    const float* mu_[3] = {(const float*)d_in[4],  (const float*)d_in[9],  (const float*)d_in[14]};
    const float* sg_[3] = {(const float*)d_in[5],  (const float*)d_in[10], (const float*)d_in[15]};
    const float* rt_[3] = {(const float*)d_in[6],  (const float*)d_in[11], (const float*)d_in[16]};
    const float* bs_[3] = {(const float*)d_in[7],  (const float*)d_in[12], (const float*)d_in[17]};
    const float* fcw = (const float*)d_in[18];
    const float* fcb = (const float*)d_in[19];
    float* out = (float*)d_out;
    (void)in_sizes; (void)n_in; (void)out_size; (void)ws_size;

    // workspace carve-up (~91 MB)
    // binbuf (dead after build_pass) aliases hA+hB (born in layers 0/1).
    char* w = (char*)d_ws;
    size_t off = 0;
    auto carve = [&](size_t bytes) -> void* {
        void* p = (void*)(w + off);
        off += (bytes + 255) & ~(size_t)255;
        return p;
    };
    int*    cnt    = (int*)carve((size_t)NN * 4);        // exact degree (build_pass output)
    int*    cursor = (int*)carve((size_t)NN * 4);        // CSR start offsets
    int*    bincnt = (int*)carve((size_t)NBIN * 4);      // per-bin edge counts
    float4* ged0   = (float4*)carve((size_t)NE * 16);    // {src, g0,g1,g2} layer 0
    float4* ged1   = (float4*)carve((size_t)NE * 16);    // layer 1
    float4* ged2   = (float4*)carve((size_t)NE * 16);    // layer 2
    unsigned short* W0 = (unsigned short*)carve((size_t)32 * 128 * 2);
    unsigned short* W1 = (unsigned short*)carve((size_t)64 * 128 * 2);
    unsigned short* W2 = (unsigned short*)carve((size_t)64 * 256 * 2);
    unsigned short* xp = (unsigned short*)carve((size_t)NN * 32 * 2);  // bf16 [N,32]
    // union region: binbuf (21 MB) | (hA 10.5 MB, hB 21 MB)
    char* uni = (char*)carve((size_t)NN * 64 * 2 + (size_t)NN * 32 * 2);
    int4*           binbuf = (int4*)uni;                               // NBIN*BINCAP*16 = 21 MB
    unsigned short* hA     = (unsigned short*)uni;                     // bf16 [N,32]
    unsigned short* hB     = (unsigned short*)(uni + (size_t)NN * 32 * 2);  // bf16 [N,64]

    const int* src = ei;
    const int* dst = ei + NE;
    const int PB = (NN + 255) / 256;  // pad blocks (641)
    const int WB = 112;               // (32*128 + 64*128 + 64*256) / 256
    const int GB = (NN + 63) / 64;    // 2561 blocks: 64 nodes per block

    // ---- two-level radix CSR build (no per-node atomics; bin prefix inlined) ----
    hipMemsetAsync(bincnt, 0, (size_t)NBIN * 4, stream);
    bin_pass<<<256, 256, 0, stream>>>(dst, src, ea, bincnt, binbuf);
    build_pass<<<NBIN + PB + WB, 256, 0, stream>>>(binbuf, bincnt, cnt, cursor,
                                                   mu_[0], sg_[0], mu_[1], sg_[1], mu_[2], sg_[2],
                                                   ged0, ged1, ged2, x, xp,
                                                   g_[0], rt_[0], g_[1], rt_[1], g_[2], rt_[2],
                                                   W0, W1, W2, PB, NN);

    // ---- layer 0: 22(pad32) -> 32 ----
    fused_mfma<32, 32, 256, false><<<GB, 256, 0, stream>>>(xp, 32, ged0, cursor, cnt,
                                                           W0, bs_[0], hA, nullptr, nullptr,
                                                           nullptr, NN);
    // ---- layer 1: 32 -> 64 ----
    fused_mfma<32, 64, 256, false><<<GB, 256, 0, stream>>>(hA, 32, ged1, cursor, cnt,
                                                           W1, bs_[1], hB, nullptr, nullptr,
                                                           nullptr, NN);
    // ---- layer 2: 64 -> 64, 512 threads, fused FC + log_softmax ----
    fused_mfma<64, 64, 512, true><<<GB, 512, 0, stream>>>(hB, 64, ged2, cursor, cnt,
                                                          W2, bs_[2], nullptr, fcw, fcb,
                                                          out, NN);
}

// Round 12
// 271.492 us; speedup vs baseline: 1.0806x; 1.0806x over previous
//
#include <hip/hip_runtime.h>

#define NN 163842
#define NE 983040
#define NBIN 641      // bin = dst>>8 -> 256 nodes/bin (bin 640 holds 2 nodes)
#define BINCAP 2048   // per-bin edges: mean 1536, sigma ~39 -> +13 sigma, never overflows

using short8   = __attribute__((ext_vector_type(8))) short;
using ushort8v = __attribute__((ext_vector_type(8))) unsigned short;
using f32x4    = __attribute__((ext_vector_type(4))) float;
using v2f      = __attribute__((ext_vector_type(2))) float;

static __device__ __forceinline__ unsigned short bf16rne(float x) {
    unsigned u = __float_as_uint(x);
    u += 0x7FFFu + ((u >> 16) & 1u);      // round-to-nearest-even
    return (unsigned short)(u >> 16);
}

// two bf16 (packed in a uint) -> v2f {lo, hi}
static __device__ __forceinline__ v2f bfpair(unsigned u) {
    v2f r;
    r[0] = __uint_as_float(u << 16);
    r[1] = __uint_as_float(u & 0xffff0000u);
    return r;
}

// ---- pass 1: coarse binning. Random writes become run-clustered 16-B record
// writes into per-bin regions (LDS histogram + one global atomic per block-bin).
// 256 blocks (1/CU) x 3840 edges = 983040 exactly.
__global__ __launch_bounds__(256) void bin_pass(const int* __restrict__ dst,
                                                const int* __restrict__ src,
                                                const float* __restrict__ ea,
                                                int* __restrict__ bincnt,
                                                int4* __restrict__ binbuf) {
    __shared__ int hist[NBIN], base[NBIN], pos[NBIN];
    const int t = threadIdx.x;
    for (int i = t; i < NBIN; i += 256) { hist[i] = 0; pos[i] = 0; }
    __syncthreads();
    const int e0 = blockIdx.x * 3840;
#pragma unroll 3
    for (int it = 0; it < 15; ++it) {
        int b = dst[e0 + it * 256 + t] >> 8;
        atomicAdd(&hist[b], 1);
    }
    __syncthreads();
    for (int i = t; i < NBIN; i += 256)
        if (hist[i] > 0) base[i] = atomicAdd(&bincnt[i], hist[i]);
    __syncthreads();
    for (int it = 0; it < 15; ++it) {
        int e = e0 + it * 256 + t;
        int d = dst[e];
        int b = d >> 8;
        int j = atomicAdd(&pos[b], 1);
        int slot = base[b] + j;
        float2 exy = *(const float2*)(ea + 2 * (size_t)e);
        int4 r;
        r.x = d; r.y = src[e];
        r.z = __float_as_int(exy.x); r.w = __float_as_int(exy.y);
        if (slot < BINCAP) binbuf[(size_t)b * BINCAP + slot] = r;
    }
}

// ---- transposed bf16 weights Wcb[n][k], k-major ----
template <int CIN, int CINP, int COUTR>
static __device__ __forceinline__ void wcb_emit(int t, const float* __restrict__ g,
                                                const float* __restrict__ root,
                                                unsigned short* __restrict__ Wcb) {
    constexpr int KTl = 4 * CINP;
    int nIdx = t / KTl, k = t - nIdx * KTl;
    int seg = k / CINP, c = k - seg * CINP;
    float v = 0.0f;
    if (c < CIN)
        v = (seg < 3) ? g[c * (3 * COUTR) + seg * COUTR + nIdx] : root[c * COUTR + nIdx];
    Wcb[t] = bf16rne(v);
}

// 3 gaussian weights from edge pseudo-coords; muv/ccv constant-indexed -> registers.
static __device__ __forceinline__ float3 gauss3c(float ex, float ey,
                                                 const float* muv, const float* ccv) {
    float3 r;
    float dx, dy;
    dx = ex - muv[0]; dy = ey - muv[1];
    r.x = __expf(fmaf(ccv[0] * dx, dx, ccv[1] * dy * dy));
    dx = ex - muv[2]; dy = ey - muv[3];
    r.y = __expf(fmaf(ccv[2] * dx, dx, ccv[3] * dy * dy));
    dx = ex - muv[4]; dy = ey - muv[5];
    r.z = __expf(fmaf(ccv[4] * dx, dx, ccv[5] * dy * dy));
    return r;
}

// ---- pass 2: one workgroup per bin. Inline exclusive bin-prefix; LDS 256-histogram
// + scan -> exact per-node CSR (streaming, zero global atomics); gaussians once per
// edge; ged writes land in the bin's contiguous CSR window. pad-x and Wcb appended.
__global__ __launch_bounds__(256) void build_pass(const int4* __restrict__ binbuf,
                                                  const int* __restrict__ bincnt,
                                                  int* __restrict__ cnt,
                                                  int* __restrict__ cursor,
                                                  const float* __restrict__ mu0, const float* __restrict__ sg0,
                                                  const float* __restrict__ mu1, const float* __restrict__ sg1,
                                                  const float* __restrict__ mu2, const float* __restrict__ sg2,
                                                  float4* __restrict__ ged0,
                                                  float4* __restrict__ ged1,
                                                  float4* __restrict__ ged2,
                                                  const float* __restrict__ x,
                                                  unsigned short* __restrict__ xp,
                                                  const float* __restrict__ g0, const float* __restrict__ rt0,
                                                  const float* __restrict__ g1, const float* __restrict__ rt1,
                                                  const float* __restrict__ g2, const float* __restrict__ rt2,
                                                  unsigned short* __restrict__ W0,
                                                  unsigned short* __restrict__ W1,
                                                  unsigned short* __restrict__ W2,
                                                  int PBLK, int n) {
    __shared__ int h2[256], pre[256], pos2[256];
    const int t = threadIdx.x;
    int bid = blockIdx.x;
    if (bid < NBIN) {
        // ---- inline exclusive prefix: boff = sum_{i<bid} min(bincnt[i], BINCAP) ----
        int partial = 0;
        for (int i = t; i < bid; i += 256) partial += min(bincnt[i], BINCAP);
        pre[t] = partial;
        __syncthreads();
        for (int o = 128; o > 0; o >>= 1) {
            if (t < o) pre[t] += pre[t + o];
            __syncthreads();
        }
        const int boff = pre[0];

        float muv0[6], ccv0[6], muv1[6], ccv1[6], muv2[6], ccv2[6];
#pragma unroll
        for (int j = 0; j < 6; ++j) {
            muv0[j] = mu0[j]; muv1[j] = mu1[j]; muv2[j] = mu2[j];
            float s0 = sg0[j], s1 = sg1[j], s2 = sg2[j];
            ccv0[j] = -0.5f / (1e-15f + s0 * s0);
            ccv1[j] = -0.5f / (1e-15f + s1 * s1);
            ccv2[j] = -0.5f / (1e-15f + s2 * s2);
        }
        const int total = min(bincnt[bid], BINCAP);
        const int4* bb  = binbuf + (size_t)bid * BINCAP;
        h2[t] = 0; pos2[t] = 0;
        __syncthreads();                           // also fences boff read before pre reuse
        for (int i = t; i < total; i += 256) atomicAdd(&h2[bb[i].x & 255], 1);
        __syncthreads();
        pre[t] = h2[t];
        __syncthreads();
        for (int o = 1; o < 256; o <<= 1) {
            int v = (t >= o) ? pre[t - o] : 0;
            __syncthreads();
            pre[t] += v;
            __syncthreads();
        }
        pre[t] -= h2[t];                           // exclusive
        int node = (bid << 8) + t;
        if (node < n) { cnt[node] = h2[t]; cursor[node] = boff + pre[t]; }
        __syncthreads();                           // pre[] final before random reads
        for (int i = t; i < total; i += 256) {
            int4 r = bb[i];
            int l = r.x & 255;
            int j = atomicAdd(&pos2[l], 1);
            int p = boff + pre[l] + j;
            float exf = __int_as_float(r.z), eyf = __int_as_float(r.w);
            float sb  = __int_as_float(r.y);       // src bits
            float3 G0 = gauss3c(exf, eyf, muv0, ccv0);
            float3 G1 = gauss3c(exf, eyf, muv1, ccv1);
            float3 G2 = gauss3c(exf, eyf, muv2, ccv2);
            ged0[p] = make_float4(sb, G0.x, G0.y, G0.z);
            ged1[p] = make_float4(sb, G1.x, G1.y, G1.z);
            ged2[p] = make_float4(sb, G2.x, G2.y, G2.z);
        }
        return;
    }
    bid -= NBIN;
    if (bid < PBLK) {
        // ---- pad path: one thread per node, float2 loads + ushort8 stores ----
        int r = bid * 256 + threadIdx.x;
        if (r >= n) return;
        float v[22];
        const float2* x2 = (const float2*)(x + (size_t)r * 22);  // 88 B row, 8-aligned
#pragma unroll
        for (int j = 0; j < 11; ++j) *(float2*)(v + 2 * j) = x2[j];
        unsigned short* op = xp + (size_t)r * 32;
#pragma unroll
        for (int g8 = 0; g8 < 4; ++g8) {
            ushort8v o;
#pragma unroll
            for (int j = 0; j < 8; ++j) {
                int c = g8 * 8 + j;
                o[j] = (c < 22) ? bf16rne(v[c]) : (unsigned short)0;
            }
            *(ushort8v*)(op + g8 * 8) = o;
        }
        return;
    }
    bid -= PBLK;
    int tt = bid * 256 + threadIdx.x;
    constexpr int T0 = 32 * 128, T1 = 64 * 128, T2 = 64 * 256;
    if (tt < T0)                wcb_emit<22, 32, 32>(tt, g0, rt0, W0);
    else if (tt < T0 + T1)      wcb_emit<32, 32, 64>(tt - T0, g1, rt1, W1);
    else if (tt < T0 + T1 + T2) wcb_emit<64, 64, 64>(tt - T0 - T1, g2, rt2, W2);
}

// ============ FUSED layer: aggregate (16-B bf16 gather) -> bf16 LDS tile -> MFMA ============
// Round-12: REVERT round-11's masked-tail gathers (divergent branches around loads
// serialized the 4-chain MLP: 48->61 us, VGPR 40->44, occ 46->37%). Back to round-10's
// clamp-to-end-1 predication: loads UNCONDITIONAL (clamped index, zeroed weight) so
// all 4 ged->h chains issue back-to-back. Plain launch bounds (min-waves pin causes
// scratch spill, r9). Suspected regime: random-L3-line path ~2.6 TB/s, 2 lines/edge
// (128-B h row) = pull-mode floor — dur invariant across batch-2/4 and occ 46-60%.
// Tile 64 x KT bf16, odd float4 stride conflict-free. MFMA C/D col=lane&15, row=quad*4+reg.
// FC=true: fused FC 64->2 + log_softmax through LDS (no hC traffic, no extra launch).
template <int CINP, int COUTR, int NT, bool FC>
__global__ __launch_bounds__(NT) void fused_mfma(const unsigned short* __restrict__ h, int hs,
                                                 const float4* __restrict__ ged,
                                                 const int* __restrict__ cursor,
                                                 const int* __restrict__ degi,
                                                 const unsigned short* __restrict__ Wcb,
                                                 const float* __restrict__ bias,
                                                 unsigned short* __restrict__ out,
                                                 const float* __restrict__ fcw,
                                                 const float* __restrict__ fcb,
                                                 float* __restrict__ fout, int n) {
    constexpr int KT    = 4 * CINP;
    constexpr int ST4   = KT / 8 + 1;            // float4 per LDS row (odd)
    constexpr int ROWU  = ST4 * 8;               // ushorts per LDS row
    constexpr int NSTEP = KT / 32;
    constexpr int NCT   = COUTR / 16;
    constexpr int LPN   = CINP / 8;              // lanes per node
    constexpr int NPP   = NT / LPN;              // nodes per pass
    static_assert(NPP == 64, "single pass over the 64-node tile");
    __shared__ float4 sa[64 * ST4];
    unsigned short* st = (unsigned short*)sa;
    const int row0 = blockIdx.x * 64;

    // ---------------- phase 1: aggregate + own-h into bf16 LDS tile ----------------
    {
        const int sub = threadIdx.x / LPN;
        const int li  = threadIdx.x % LPN;       // covers bf16 [li*8, li*8+8)
        int node = row0 + sub; if (node > n - 1) node = n - 1;
        int p   = cursor[node];                  // start
        int dg  = degi[node];                    // exact degree
        int end = p + dg;
        v2f a[3][4];
#pragma unroll
        for (int k = 0; k < 3; ++k)
#pragma unroll
            for (int q = 0; q < 4; ++q) a[k][q] = (v2f){0.0f, 0.0f};
        for (; p < end; p += 4) {                // predicated batch-4: 4 chains in flight
            float4 ed[4];
            uint4  hu[4];
#pragma unroll
            for (int u = 0; u < 4; ++u) {
                int q = p + u;
                ed[u] = ged[(q < end) ? q : (end - 1)];
            }
#pragma unroll
            for (int u = 0; u < 4; ++u)
                hu[u] = *(const uint4*)(h + (long)__float_as_int(ed[u].x) * hs + li * 8);
#pragma unroll
            for (int u = 0; u < 4; ++u)
                if (p + u >= end) { ed[u].y = 0.0f; ed[u].z = 0.0f; ed[u].w = 0.0f; }
#pragma unroll
            for (int u = 0; u < 4; ++u) {
                v2f hv[4] = {bfpair(hu[u].x), bfpair(hu[u].y), bfpair(hu[u].z), bfpair(hu[u].w)};
#pragma unroll
                for (int q = 0; q < 4; ++q) {
                    a[0][q] += hv[q] * ed[u].y;
                    a[1][q] += hv[q] * ed[u].z;
                    a[2][q] += hv[q] * ed[u].w;
                }
            }
        }
        float inv = 1.0f / (float)max(dg, 1);
#pragma unroll
        for (int k = 0; k < 3; ++k)
#pragma unroll
            for (int q = 0; q < 4; ++q) a[k][q] *= inv;
        uint4 hv4 = *(const uint4*)(h + (long)node * hs + li * 8);   // raw bf16 own row
        int base = sub * ROWU;
        int c8b  = li * 8;
#pragma unroll
        for (int k = 0; k < 3; ++k) {
            ushort8v v;
#pragma unroll
            for (int q = 0; q < 4; ++q) {
                v[2 * q]     = bf16rne(a[k][q][0]);
                v[2 * q + 1] = bf16rne(a[k][q][1]);
            }
            *(ushort8v*)(st + base + k * CINP + c8b) = v;
        }
        *(uint4*)(st + base + 3 * CINP + c8b) = hv4;
    }
    __syncthreads();

    // ---------------- phase 2: MFMA GEMM from LDS tile ----------------
    constexpr int NW    = NT / 64;               // waves per block
    constexpr int TILES = 4 * NCT;               // 4 row-groups x NCT col-tiles
    constexpr int TPW   = TILES / NW;
    constexpr int RST   = NW / NCT;              // row-group stride per wave
    static_assert(NW % NCT == 0 && TILES % NW == 0, "tile remap");
    const int lane = threadIdx.x & 63;
    const int wv   = threadIdx.x >> 6;
    const int quad = lane >> 4;
    const int c16  = lane & 15;
    const int ct   = wv % NCT;                   // fixed column-tile per wave
    const int rg0  = wv / NCT;
    f32x4 acc[TPW];
#pragma unroll
    for (int i = 0; i < TPW; ++i) acc[i] = (f32x4){0.0f, 0.0f, 0.0f, 0.0f};
    const unsigned short* bcol = Wcb + (ct * 16 + c16) * KT;
#pragma unroll
    for (int s = 0; s < NSTEP; ++s) {
        short8 bf = *(const short8*)(bcol + s * 32 + quad * 8);  // hoisted: same ct all tiles
#pragma unroll
        for (int i = 0; i < TPW; ++i) {
            const unsigned short* arow = st + (16 * (rg0 + i * RST) + c16) * ROWU;
            short8 af = *(const short8*)(arow + s * 32 + quad * 8);
            acc[i] = __builtin_amdgcn_mfma_f32_16x16x32_bf16(af, bf, acc[i], 0, 0, 0);
        }
    }
    if constexpr (!FC) {
        // epilogue: C/D col=lane&15, row=quad*4+reg; write bf16
#pragma unroll
        for (int i = 0; i < TPW; ++i) {
            int rg  = rg0 + i * RST;
            int col = ct * 16 + c16;
            float b = bias[col];
#pragma unroll
            for (int r = 0; r < 4; ++r) {
                int grow = row0 + rg * 16 + quad * 4 + r;
                if (grow < n)
                    out[(long)grow * COUTR + col] = bf16rne(fmaxf(acc[i][r] + b, 0.0f));
            }
        }
    } else {
        // fused FC(64->2)+log_softmax: relu'd bf16 row -> LDS (reuse sa) -> per-node dot
        static_assert(COUTR == 64, "FC fusion assumes 64-wide rows");
        constexpr int FS = 72;                   // ushort stride, 144 B rows (16-B aligned)
        __syncthreads();                         // all MFMA LDS reads complete
        {
            int col = ct * 16 + c16;
            float b = bias[col];
#pragma unroll
            for (int i = 0; i < TPW; ++i) {
                int rg = rg0 + i * RST;
#pragma unroll
                for (int r = 0; r < 4; ++r) {
                    int lr2 = rg * 16 + quad * 4 + r;
                    st[lr2 * FS + col] = bf16rne(fmaxf(acc[i][r] + b, 0.0f));
                }
            }
        }
        __syncthreads();
        int t = threadIdx.x;
        if (t < 64) {
            int node = row0 + t;
            if (node < n) {
                const ushort8v* hr = (const ushort8v*)(st + t * FS);
                float l0 = fcb[0];
                float l1 = fcb[1];
#pragma unroll
                for (int j8 = 0; j8 < 8; ++j8) {
                    ushort8v hv = hr[j8];
#pragma unroll
                    for (int j = 0; j < 8; ++j) {
                        float hvf = __uint_as_float(((unsigned)hv[j]) << 16);
                        l0 = fmaf(hvf, fcw[2 * (8 * j8 + j)], l0);
                        l1 = fmaf(hvf, fcw[2 * (8 * j8 + j) + 1], l1);
                    }
                }
                float mx  = fmaxf(l0, l1);
                float lse = mx + logf(__expf(l0 - mx) + __expf(l1 - mx));
                fout[2 * (long)node]     = l0 - lse;
                fout[2 * (long)node + 1] = l1 - lse;
            }
        }
    }
}

extern "C" void kernel_launch(void* const* d_in, const int* in_sizes, int n_in,
                              void* d_out, int out_size, void* d_ws, size_t ws_size,
                              hipStream_t stream) {
    const float* x   = (const float*)d_in[0];
    const int*   ei  = (const int*)d_in[1];
    const float* ea  = (const float*)d_in[2];
    const float* g_[3]  = {(const float*)d_in[3],  (const float*)d_in[8],  (const float*)d_in[13]};
    const float* mu_[3] = {(const float*)d_in[4],  (const float*)d_in[9],  (const float*)d_in[14]};
    const float* sg_[3] = {(const float*)d_in[5],  (const float*)d_in[10], (const float*)d_in[15]};
    const float* rt_[3] = {(const float*)d_in[6],  (const float*)d_in[11], (const float*)d_in[16]};
    const float* bs_[3] = {(const float*)d_in[7],  (const float*)d_in[12], (const float*)d_in[17]};
    const float* fcw = (const float*)d_in[18];
    const float* fcb = (const float*)d_in[19];
    float* out = (float*)d_out;
    (void)in_sizes; (void)n_in; (void)out_size; (void)ws_size;

    // workspace carve-up (~91 MB)
    // binbuf (dead after build_pass) aliases hA+hB (born in layers 0/1).
    char* w = (char*)d_ws;
    size_t off = 0;
    auto carve = [&](size_t bytes) -> void* {
        void* p = (void*)(w + off);
        off += (bytes + 255) & ~(size_t)255;
        return p;
    };
    int*    cnt    = (int*)carve((size_t)NN * 4);        // exact degree (build_pass output)
    int*    cursor = (int*)carve((size_t)NN * 4);        // CSR start offsets
    int*    bincnt = (int*)carve((size_t)NBIN * 4);      // per-bin edge counts
    float4* ged0   = (float4*)carve((size_t)NE * 16);    // {src, g0,g1,g2} layer 0
    float4* ged1   = (float4*)carve((size_t)NE * 16);    // layer 1
    float4* ged2   = (float4*)carve((size_t)NE * 16);    // layer 2
    unsigned short* W0 = (unsigned short*)carve((size_t)32 * 128 * 2);
    unsigned short* W1 = (unsigned short*)carve((size_t)64 * 128 * 2);
    unsigned short* W2 = (unsigned short*)carve((size_t)64 * 256 * 2);
    unsigned short* xp = (unsigned short*)carve((size_t)NN * 32 * 2);  // bf16 [N,32]
    // union region: binbuf (21 MB) | (hA 10.5 MB, hB 21 MB)
    char* uni = (char*)carve((size_t)NN * 64 * 2 + (size_t)NN * 32 * 2);
    int4*           binbuf = (int4*)uni;                               // NBIN*BINCAP*16 = 21 MB
    unsigned short* hA     = (unsigned short*)uni;                     // bf16 [N,32]
    unsigned short* hB     = (unsigned short*)(uni + (size_t)NN * 32 * 2);  // bf16 [N,64]

    const int* src = ei;
    const int* dst = ei + NE;
    const int PB = (NN + 255) / 256;  // pad blocks (641)
    const int WB = 112;               // (32*128 + 64*128 + 64*256) / 256
    const int GB = (NN + 63) / 64;    // 2561 blocks: 64 nodes per block

    // ---- two-level radix CSR build (no per-node atomics; bin prefix inlined) ----
    hipMemsetAsync(bincnt, 0, (size_t)NBIN * 4, stream);
    bin_pass<<<256, 256, 0, stream>>>(dst, src, ea, bincnt, binbuf);
    build_pass<<<NBIN + PB + WB, 256, 0, stream>>>(binbuf, bincnt, cnt, cursor,
                                                   mu_[0], sg_[0], mu_[1], sg_[1], mu_[2], sg_[2],
                                                   ged0, ged1, ged2, x, xp,
                                                   g_[0], rt_[0], g_[1], rt_[1], g_[2], rt_[2],
                                                   W0, W1, W2, PB, NN);

    // ---- layer 0: 22(pad32) -> 32 ----
    fused_mfma<32, 32, 256, false><<<GB, 256, 0, stream>>>(xp, 32, ged0, cursor, cnt,
                                                           W0, bs_[0], hA, nullptr, nullptr,
                                                           nullptr, NN);
    // ---- layer 1: 32 -> 64 ----
    fused_mfma<32, 64, 256, false><<<GB, 256, 0, stream>>>(hA, 32, ged1, cursor, cnt,
                                                           W1, bs_[1], hB, nullptr, nullptr,
                                                           nullptr, NN);
    // ---- layer 2: 64 -> 64, 512 threads, fused FC + log_softmax ----
    fused_mfma<64, 64, 512, true><<<GB, 512, 0, stream>>>(hB, 64, ged2, cursor, cnt,
                                                          W2, bs_[2], nullptr, fcw, fcb,
                                                          out, NN);
}